// Round 2
// baseline (1219.383 us; speedup 1.0000x reference)
//
#include <hip/hip_runtime.h>

typedef unsigned short u16;
typedef short bf16x8 __attribute__((ext_vector_type(8)));
typedef float f32x4 __attribute__((ext_vector_type(4)));

__device__ __forceinline__ float bf2f(unsigned v) { return __uint_as_float(v << 16); }
__device__ __forceinline__ u16 f2bf(float f) {
    unsigned u = __float_as_uint(f);
    return (u16)((u + 0x7fffu + ((u >> 16) & 1u)) >> 16);
}

// ---- async global->LDS, width 16B per lane, dest = wave base + lane*16 ----
__device__ __forceinline__ void gload_lds16(const void* g, void* l) {
    __builtin_amdgcn_global_load_lds(
        (const __attribute__((address_space(1))) unsigned int*)g,
        (__attribute__((address_space(3))) unsigned int*)l, 16, 0, 0);
}

// =====================================================================
// Bitmask: bit j of word w  <=>  adj[w*32 + j] > 0   (adj fp32)
__global__ __launch_bounds__(256) void k_mask(const float* __restrict__ adj,
                                              unsigned* __restrict__ mask) {
    int w = blockIdx.x * 256 + threadIdx.x;           // 524288 words
    const float4* q = (const float4*)(adj + (size_t)w * 32);
    unsigned bits = 0u;
#pragma unroll
    for (int i = 0; i < 8; i++) {
        float4 v = q[i];
        if (v.x > 0.f) bits |= (1u << (i * 4 + 0));
        if (v.y > 0.f) bits |= (1u << (i * 4 + 1));
        if (v.z > 0.f) bits |= (1u << (i * 4 + 2));
        if (v.w > 0.f) bits |= (1u << (i * 4 + 3));
    }
    mask[w] = bits;
}

// =====================================================================
// Transpose [K,128] fp32 -> [128,K] bf16 per matrix (batch = blockIdx.z)
__global__ void k_trans(const float* __restrict__ in, u16* __restrict__ out, int K) {
    __shared__ float t[32][33];
    const float* src = in + (size_t)blockIdx.z * K * 128;
    u16* dst = out + (size_t)blockIdx.z * K * 128;
    int k0 = blockIdx.x * 32, n0 = blockIdx.y * 32;
    int tx = threadIdx.x, ty = threadIdx.y;           // 32 x 8
#pragma unroll
    for (int i = 0; i < 32; i += 8) t[ty + i][tx] = src[(size_t)(k0 + ty + i) * 128 + n0 + tx];
    __syncthreads();
#pragma unroll
    for (int i = 0; i < 32; i += 8) dst[(size_t)(n0 + ty + i) * K + k0 + tx] = f2bf(t[tx][ty + i]);
}

// =====================================================================
// fp32 -> bf16 elementwise (entity embedding), 4 elems/thread
__global__ __launch_bounds__(256) void k_cvt(const float* __restrict__ in,
                                             u16* __restrict__ out) {
    int t = blockIdx.x * 256 + threadIdx.x;
    float4 v = ((const float4*)in)[t];
    uint2 o;
    o.x = (unsigned)f2bf(v.x) | ((unsigned)f2bf(v.y) << 16);
    o.y = (unsigned)f2bf(v.z) | ((unsigned)f2bf(v.w) << 16);
    ((uint2*)out)[t] = o;
}

// =====================================================================
// Projection: Wh = x @ W_h  (M=4096, N=128, K=Fin). X bf16, WT bf16 [n][k],
// avec fp32. Writes WhT[n][j] bf16 and f1/f2 fp32.  256 thr, tile 64x128.
__global__ __launch_bounds__(256) void k_proj(const u16* __restrict__ X,
                                              const u16* __restrict__ WT,
                                              const float* __restrict__ avec,
                                              u16* __restrict__ WhT,
                                              float* __restrict__ f1,
                                              float* __restrict__ f2, int Fin) {
    __shared__ u16 As[64 * 32];    // [row][k]
    __shared__ u16 Bs[128 * 32];   // [n][k]
    const int tid = threadIdx.x;
    const int wv = tid >> 6, lane = tid & 63;
    const int c = lane & 15, quad = lane >> 4;
    const int h = blockIdx.y;
    const int j0 = blockIdx.x * 64;
    const u16* Wp = WT + (size_t)h * 128 * Fin;

    f32x4 acc[8];
#pragma unroll
    for (int i = 0; i < 8; i++) acc[i] = (f32x4){0.f, 0.f, 0.f, 0.f};

    for (int kb = 0; kb < Fin; kb += 32) {
        __syncthreads();
        gload_lds16(X + (size_t)(j0 + wv * 16 + (lane >> 2)) * Fin + kb + (lane & 3) * 8,
                    (void*)&As[wv * 16 * 32]);
#pragma unroll
        for (int e = 0; e < 2; e++) {
            int qi = wv * 2 + e;
            gload_lds16(Wp + (size_t)(qi * 16 + (lane >> 2)) * Fin + kb + (lane & 3) * 8,
                        (void*)&Bs[qi * 16 * 32]);
        }
        __syncthreads();
        bf16x8 av = *(const bf16x8*)&As[(wv * 16 + c) * 32 + quad * 8];
#pragma unroll
        for (int nt = 0; nt < 8; nt++) {
            bf16x8 bv = *(const bf16x8*)&Bs[(nt * 16 + c) * 32 + quad * 8];
            acc[nt] = __builtin_amdgcn_mfma_f32_16x16x32_bf16(av, bv, acc[nt], 0, 0, 0);
        }
    }

    // epilogue: D row (=x-row j) = wv*16+quad*4+r, col (=n) = nt*16+c
    u16* Wo = WhT + (size_t)h * 128 * 4096;
    const float* ah = avec + h * 256;
    float p1[4] = {0, 0, 0, 0}, p2[4] = {0, 0, 0, 0};
#pragma unroll
    for (int nt = 0; nt < 8; nt++) {
        float a1 = ah[nt * 16 + c];
        float a2 = ah[128 + nt * 16 + c];
        u16 w4[4];
#pragma unroll
        for (int r = 0; r < 4; r++) {
            float v = acc[nt][r];
            w4[r] = f2bf(v);
            p1[r] += v * a1;
            p2[r] += v * a2;
        }
        uint2 pk;
        pk.x = (unsigned)w4[0] | ((unsigned)w4[1] << 16);
        pk.y = (unsigned)w4[2] | ((unsigned)w4[3] << 16);
        *(uint2*)&Wo[(size_t)(nt * 16 + c) * 4096 + j0 + wv * 16 + quad * 4] = pk;
    }
#pragma unroll
    for (int off = 1; off < 16; off <<= 1) {
#pragma unroll
        for (int r = 0; r < 4; r++) {
            p1[r] += __shfl_xor(p1[r], off);
            p2[r] += __shfl_xor(p2[r], off);
        }
    }
    if (c == 0) {
#pragma unroll
        for (int r = 0; r < 4; r++) {
            int j = j0 + wv * 16 + quad * 4 + r;
            f1[h * 4096 + j] = p1[r];
            f2[h * 4096 + j] = p2[r];
        }
    }
}

// =====================================================================
// Fused masked softmax attention + ELU.
// P_ij = mask_ij * exp(LR(f1_i+f2_j) - LR(f1_i + max_all f2)); out = elu(P@Wh / l)
// Block: 256 thr, 64 query rows, all 128 cols, K-loop over j in steps of 32.
template <bool F32OUT>
__global__ __launch_bounds__(256) void k_attn(const u16* __restrict__ WhT,
                                              const float* __restrict__ f1g,
                                              const float* __restrict__ f2g,
                                              const unsigned char* __restrict__ maskb,
                                              void* __restrict__ outp, int ostride) {
    __shared__ float f2s[4096];            // 16 KB
    __shared__ unsigned char ms[64 * 528]; // padded mask rows, 33 KB
    __shared__ u16 Bs[128 * 32];           // WhT tile [n][k], 8 KB
    __shared__ float f1s[64];
    __shared__ float lrow[4][16];
    __shared__ float red[4];

    const int tid = threadIdx.x;
    const int wv = tid >> 6, lane = tid & 63;
    const int c = lane & 15, quad = lane >> 4;
    const int h = blockIdx.y;
    const int i0 = blockIdx.x * 64;
    const float* f1h = f1g + h * 4096;
    const float* f2h = f2g + h * 4096;
    const u16* Wp = WhT + (size_t)h * 128 * 4096;

    float mymax = -3.0e38f;
#pragma unroll
    for (int i = 0; i < 4; i++) {
        float4 v = ((const float4*)f2h)[tid * 4 + i];
        ((float4*)f2s)[tid * 4 + i] = v;
        mymax = fmaxf(mymax, fmaxf(fmaxf(v.x, v.y), fmaxf(v.z, v.w)));
    }
    if (tid < 64) f1s[tid] = f1h[i0 + tid];
    {   // 64 rows x 512 B of mask = 2048 uint4
        const uint4* msrc = (const uint4*)(maskb + (size_t)i0 * 512);
#pragma unroll
        for (int e = 0; e < 8; e++) {
            int o = tid + e * 256;
            uint4 v = msrc[o];
            int row = o >> 5, col = o & 31;
            *(uint4*)&ms[row * 528 + col * 16] = v;
        }
    }
#pragma unroll
    for (int off = 1; off < 64; off <<= 1) mymax = fmaxf(mymax, __shfl_xor(mymax, off));
    if (lane == 0) red[wv] = mymax;
    __syncthreads();
    const float F2MAX = fmaxf(fmaxf(red[0], red[1]), fmaxf(red[2], red[3]));
    const int iloc = wv * 16 + c;                    // A-fragment row (m = lane&15)
    const float rf1 = f1s[iloc];
    const float zb = rf1 + F2MAX;
    const float rm = fmaxf(zb, 0.2f * zb);           // LR(f1_i + F2MAX) >= any row score

    f32x4 acc[8];
#pragma unroll
    for (int i = 0; i < 8; i++) acc[i] = (f32x4){0.f, 0.f, 0.f, 0.f};
    float lsum = 0.f;

    for (int kb = 0; kb < 128; kb++) {
        const int jb = kb * 32;
        __syncthreads();
#pragma unroll
        for (int e = 0; e < 2; e++) {
            int qi = wv * 2 + e;
            gload_lds16(Wp + (size_t)(qi * 16 + (lane >> 2)) * 4096 + jb + (lane & 3) * 8,
                        (void*)&Bs[qi * 16 * 32]);
        }
        __syncthreads();
        const unsigned mb = ms[iloc * 528 + kb * 4 + quad];
        const float4 fa = *(const float4*)&f2s[jb + quad * 8];
        const float4 fb = *(const float4*)&f2s[jb + quad * 8 + 4];
        const float f2v[8] = {fa.x, fa.y, fa.z, fa.w, fb.x, fb.y, fb.z, fb.w};
        union { bf16x8 v; u16 s[8]; } af;
#pragma unroll
        for (int t = 0; t < 8; t++) {
            float z = rf1 + f2v[t];
            float s = fmaxf(z, 0.2f * z) - rm;        // LeakyReLU then shift; s <= 0
            float p = ((mb >> t) & 1u) ? __expf(s) : 0.f;
            lsum += p;
            af.s[t] = f2bf(p);
        }
#pragma unroll
        for (int nt = 0; nt < 8; nt++) {
            bf16x8 bv = *(const bf16x8*)&Bs[(nt * 16 + c) * 32 + quad * 8];
            acc[nt] = __builtin_amdgcn_mfma_f32_16x16x32_bf16(af.v, bv, acc[nt], 0, 0, 0);
        }
    }

    // row denominator: lanes {c, c+16, c+32, c+48} hold partials of row iloc
    lsum += __shfl_xor(lsum, 16);
    lsum += __shfl_xor(lsum, 32);
    if (quad == 0) lrow[wv][c] = lsum;
    __syncthreads();
    const int ocol = h * 128;
#pragma unroll
    for (int nt = 0; nt < 8; nt++) {
#pragma unroll
        for (int r = 0; r < 4; r++) {
            const float l = lrow[wv][quad * 4 + r];
            float v = acc[nt][r] / l;
            float e = v > 0.f ? v : __expf(v) - 1.f;  // ELU
            size_t oidx = (size_t)(i0 + wv * 16 + quad * 4 + r) * ostride + ocol + nt * 16 + c;
            if (F32OUT) ((float*)outp)[oidx] = e;
            else        ((u16*)outp)[oidx] = f2bf(e);
        }
    }
}

// =====================================================================
// head_relation_combined = entity_emb[head] + relation_emb[relation] (fp32)
__global__ __launch_bounds__(256) void k_gather(const int* __restrict__ head,
                                                const int* __restrict__ rel,
                                                const float* __restrict__ ent,
                                                const float* __restrict__ rele,
                                                float* __restrict__ out) {
    int t = blockIdx.x * 256 + threadIdx.x;   // 131072 threads: row*32 + seg
    int row = t >> 5, sg = t & 31;
    int hh = head[row], rr = rel[row];
    float4 a = ((const float4*)(ent + (size_t)hh * 128))[sg];
    float4 b = ((const float4*)(rele + (size_t)rr * 128))[sg];
    float4 o;
    o.x = a.x + b.x; o.y = a.y + b.y; o.z = a.z + b.z; o.w = a.w + b.w;
    ((float4*)(out + (size_t)row * 128))[sg] = o;
}

// =====================================================================
extern "C" void kernel_launch(void* const* d_in, const int* in_sizes, int n_in,
                              void* d_out, int out_size, void* d_ws, size_t ws_size,
                              hipStream_t stream) {
    const int*   head = (const int*)d_in[0];
    const int*   rel  = (const int*)d_in[1];
    const float* adj  = (const float*)d_in[2];
    const float* ent  = (const float*)d_in[3];
    const float* rele = (const float*)d_in[4];
    const float* W0   = (const float*)d_in[5];
    const float* a0   = (const float*)d_in[6];
    const float* Wm   = (const float*)d_in[7];
    const float* am   = (const float*)d_in[8];
    const float* Wo   = (const float*)d_in[9];
    const float* ao   = (const float*)d_in[10];

    char* ws = (char*)d_ws;
    unsigned* mask = (unsigned*)(ws + 0);                 // 2 MB
    u16* WT0 = (u16*)(ws + 2097152);                      // 128 KB
    u16* WT5 = (u16*)(ws + 2228224);                      // 37 * 128 KB = 4.625 MB
    u16* WhT = (u16*)(ws + 7077888);                      // 4 MB
    float* f1 = (float*)(ws + 11272192);                  // 64 KB
    float* f2 = (float*)(ws + 11337728);                  // 64 KB
    u16* xA = (u16*)(ws + 11403264);                      // 4 MB
    u16* xB = (u16*)(ws + 15597568);                      // 4 MB
    u16* x0 = (u16*)(ws + 19791872);                      // 1 MB   (total ~20 MB)

    float* out_x = (float*)d_out;
    float* out_comb = out_x + (size_t)4096 * 128;

    k_mask<<<2048, 256, 0, stream>>>(adj, mask);
    k_cvt<<<512, 256, 0, stream>>>(ent, x0);
    k_trans<<<dim3(4, 4, 4), dim3(32, 8), 0, stream>>>(W0, WT0, 128);
    k_trans<<<dim3(16, 4, 36), dim3(32, 8), 0, stream>>>(Wm, WT5, 512);
    k_trans<<<dim3(16, 4, 1), dim3(32, 8), 0, stream>>>(Wo, WT5 + (size_t)36 * 512 * 128, 512);
    k_gather<<<512, 256, 0, stream>>>(head, rel, ent, rele, out_comb);

    // layer 0 : D -> H*D
    k_proj<<<dim3(64, 4), 256, 0, stream>>>(x0, WT0, a0, WhT, f1, f2, 128);
    k_attn<false><<<dim3(64, 4), 256, 0, stream>>>(WhT, f1, f2, (const unsigned char*)mask, xA, 512);
    u16 *xc = xA, *xn = xB;
    // 9 middle layers : H*D -> H*D
    for (int l = 0; l < 9; l++) {
        k_proj<<<dim3(64, 4), 256, 0, stream>>>(xc, WT5 + (size_t)l * 4 * 512 * 128,
                                                am + (size_t)l * 4 * 256, WhT, f1, f2, 512);
        k_attn<false><<<dim3(64, 4), 256, 0, stream>>>(WhT, f1, f2, (const unsigned char*)mask, xn, 512);
        u16* t = xc; xc = xn; xn = t;
    }
    // output layer : H*D -> D, single head, fp32 out
    k_proj<<<dim3(64, 1), 256, 0, stream>>>(xc, WT5 + (size_t)36 * 512 * 128, ao, WhT, f1, f2, 512);
    k_attn<true><<<dim3(64, 1), 256, 0, stream>>>(WhT, f1, f2, (const unsigned char*)mask, out_x, 128);
}

// Round 3
// 846.152 us; speedup vs baseline: 1.4411x; 1.4411x over previous
//
#include <hip/hip_runtime.h>

typedef unsigned short u16;
typedef short bf16x8 __attribute__((ext_vector_type(8)));
typedef float f32x4 __attribute__((ext_vector_type(4)));

__device__ __forceinline__ float bf2f(unsigned v) { return __uint_as_float(v << 16); }
__device__ __forceinline__ u16 f2bf(float f) {
    unsigned u = __float_as_uint(f);
    return (u16)((u + 0x7fffu + ((u >> 16) & 1u)) >> 16);
}

// ---- async global->LDS, width 16B per lane, dest = wave base + lane*16 ----
__device__ __forceinline__ void gload_lds16(const void* g, void* l) {
    __builtin_amdgcn_global_load_lds(
        (const __attribute__((address_space(1))) unsigned int*)g,
        (__attribute__((address_space(3))) unsigned int*)l, 16, 0, 0);
}

// =====================================================================
// Bitmask: bit j of word w  <=>  adj[w*32 + j] > 0   (adj fp32)
__global__ __launch_bounds__(256) void k_mask(const float* __restrict__ adj,
                                              unsigned* __restrict__ mask) {
    int w = blockIdx.x * 256 + threadIdx.x;           // 524288 words
    const float4* q = (const float4*)(adj + (size_t)w * 32);
    unsigned bits = 0u;
#pragma unroll
    for (int i = 0; i < 8; i++) {
        float4 v = q[i];
        if (v.x > 0.f) bits |= (1u << (i * 4 + 0));
        if (v.y > 0.f) bits |= (1u << (i * 4 + 1));
        if (v.z > 0.f) bits |= (1u << (i * 4 + 2));
        if (v.w > 0.f) bits |= (1u << (i * 4 + 3));
    }
    mask[w] = bits;
}

// =====================================================================
// Transpose [K,128] fp32 -> [128,K] bf16 per matrix (batch = blockIdx.z)
__global__ void k_trans(const float* __restrict__ in, u16* __restrict__ out, int K) {
    __shared__ float t[32][33];
    const float* src = in + (size_t)blockIdx.z * K * 128;
    u16* dst = out + (size_t)blockIdx.z * K * 128;
    int k0 = blockIdx.x * 32, n0 = blockIdx.y * 32;
    int tx = threadIdx.x, ty = threadIdx.y;           // 32 x 8
#pragma unroll
    for (int i = 0; i < 32; i += 8) t[ty + i][tx] = src[(size_t)(k0 + ty + i) * 128 + n0 + tx];
    __syncthreads();
#pragma unroll
    for (int i = 0; i < 32; i += 8) dst[(size_t)(n0 + ty + i) * K + k0 + tx] = f2bf(t[tx][ty + i]);
}

// =====================================================================
// fp32 -> bf16 elementwise (entity embedding), 4 elems/thread
__global__ __launch_bounds__(256) void k_cvt(const float* __restrict__ in,
                                             u16* __restrict__ out) {
    int t = blockIdx.x * 256 + threadIdx.x;
    float4 v = ((const float4*)in)[t];
    uint2 o;
    o.x = (unsigned)f2bf(v.x) | ((unsigned)f2bf(v.y) << 16);
    o.y = (unsigned)f2bf(v.z) | ((unsigned)f2bf(v.w) << 16);
    ((uint2*)out)[t] = o;
}

// =====================================================================
// Projection: Wh = x @ W_h  (M=4096, N=128, K=Fin). X bf16, WT bf16 [n][k],
// avec fp32. Writes WhT[n][j] bf16 and f1/f2 fp32.  256 thr, tile 64x128.
__global__ __launch_bounds__(256) void k_proj(const u16* __restrict__ X,
                                              const u16* __restrict__ WT,
                                              const float* __restrict__ avec,
                                              u16* __restrict__ WhT,
                                              float* __restrict__ f1,
                                              float* __restrict__ f2, int Fin) {
    __shared__ u16 As[64 * 32];    // [row][k]
    __shared__ u16 Bs[128 * 32];   // [n][k]
    const int tid = threadIdx.x;
    const int wv = tid >> 6, lane = tid & 63;
    const int c = lane & 15, quad = lane >> 4;
    const int h = blockIdx.y;
    const int j0 = blockIdx.x * 64;
    const u16* Wp = WT + (size_t)h * 128 * Fin;

    f32x4 acc[8];
#pragma unroll
    for (int i = 0; i < 8; i++) acc[i] = (f32x4){0.f, 0.f, 0.f, 0.f};

    for (int kb = 0; kb < Fin; kb += 32) {
        __syncthreads();
        gload_lds16(X + (size_t)(j0 + wv * 16 + (lane >> 2)) * Fin + kb + (lane & 3) * 8,
                    (void*)&As[wv * 16 * 32]);
#pragma unroll
        for (int e = 0; e < 2; e++) {
            int qi = wv * 2 + e;
            gload_lds16(Wp + (size_t)(qi * 16 + (lane >> 2)) * Fin + kb + (lane & 3) * 8,
                        (void*)&Bs[qi * 16 * 32]);
        }
        __syncthreads();
        bf16x8 av = *(const bf16x8*)&As[(wv * 16 + c) * 32 + quad * 8];
#pragma unroll
        for (int nt = 0; nt < 8; nt++) {
            bf16x8 bv = *(const bf16x8*)&Bs[(nt * 16 + c) * 32 + quad * 8];
            acc[nt] = __builtin_amdgcn_mfma_f32_16x16x32_bf16(av, bv, acc[nt], 0, 0, 0);
        }
    }

    // epilogue: D row (=x-row j) = wv*16+quad*4+r, col (=n) = nt*16+c
    u16* Wo = WhT + (size_t)h * 128 * 4096;
    const float* ah = avec + h * 256;
    float p1[4] = {0, 0, 0, 0}, p2[4] = {0, 0, 0, 0};
#pragma unroll
    for (int nt = 0; nt < 8; nt++) {
        float a1 = ah[nt * 16 + c];
        float a2 = ah[128 + nt * 16 + c];
        u16 w4[4];
#pragma unroll
        for (int r = 0; r < 4; r++) {
            float v = acc[nt][r];
            w4[r] = f2bf(v);
            p1[r] += v * a1;
            p2[r] += v * a2;
        }
        uint2 pk;
        pk.x = (unsigned)w4[0] | ((unsigned)w4[1] << 16);
        pk.y = (unsigned)w4[2] | ((unsigned)w4[3] << 16);
        *(uint2*)&Wo[(size_t)(nt * 16 + c) * 4096 + j0 + wv * 16 + quad * 4] = pk;
    }
#pragma unroll
    for (int off = 1; off < 16; off <<= 1) {
#pragma unroll
        for (int r = 0; r < 4; r++) {
            p1[r] += __shfl_xor(p1[r], off);
            p2[r] += __shfl_xor(p2[r], off);
        }
    }
    if (c == 0) {
#pragma unroll
        for (int r = 0; r < 4; r++) {
            int j = j0 + wv * 16 + quad * 4 + r;
            f1[h * 4096 + j] = p1[r];
            f2[h * 4096 + j] = p2[r];
        }
    }
}

// =====================================================================
// Fused masked softmax attention + ELU, j-split across 4 wave-groups.
// Block: 1024 thr = 16 waves = 4 row-groups (16 rows each) x 4 j-groups
// (1024 j's each).  Softmax shift rm uses global max(f2) so partial sums
// across j-groups combine exactly; reduced via LDS at the end.
template <bool F32OUT>
__global__ __launch_bounds__(1024, 4) void k_attn(const u16* __restrict__ WhT,
                                                  const float* __restrict__ f1g,
                                                  const float* __restrict__ f2g,
                                                  const unsigned char* __restrict__ maskb,
                                                  void* __restrict__ outp, int ostride) {
    __shared__ float f2s[4096];            // 16 KB (scaled by log2e)
    __shared__ unsigned char ms[64 * 528]; // 33 KB padded mask rows
    __shared__ u16 Bs[4][128 * 32];        // 32 KB: per-jgroup WhT tile [n][k]
    __shared__ float f1s[64];
    __shared__ float lpart[4][64];         // per-jgroup row denominators
    __shared__ float redmax[16];
    __shared__ float red[64 * 132];        // 33 KB fp32 acc reduce [i][n], pad 4

    const int tid = threadIdx.x;
    const int wv = tid >> 6, lane = tid & 63;
    const int jg = wv >> 2, rg = wv & 3;
    const int c = lane & 15, quad = lane >> 4;
    const int h = blockIdx.y;
    const int i0 = blockIdx.x * 64;
    const float LOG2E = 1.4426950408889634f;
    const float* f1h = f1g + h * 4096;
    const float* f2h = f2g + h * 4096;
    const u16* Wp = WhT + (size_t)h * 128 * 4096;

    // stage f2 (scaled), f1 (scaled), mask; block max of f2'
    float mymax = -3.0e38f;
    {
        float4 v = ((const float4*)f2h)[tid];
        v.x *= LOG2E; v.y *= LOG2E; v.z *= LOG2E; v.w *= LOG2E;
        ((float4*)f2s)[tid] = v;
        mymax = fmaxf(fmaxf(v.x, v.y), fmaxf(v.z, v.w));
    }
    if (tid < 64) f1s[tid] = f1h[i0 + tid] * LOG2E;
    {   // 64 rows x 512 B of mask = 2048 uint4
        const uint4* msrc = (const uint4*)(maskb + (size_t)i0 * 512);
#pragma unroll
        for (int e = 0; e < 2; e++) {
            int o = tid + e * 1024;
            uint4 v = msrc[o];
            int row = o >> 5, col = o & 31;
            *(uint4*)&ms[row * 528 + col * 16] = v;
        }
    }
#pragma unroll
    for (int off = 1; off < 64; off <<= 1) mymax = fmaxf(mymax, __shfl_xor(mymax, off));
    if (lane == 0) redmax[wv] = mymax;
    __syncthreads();
    float F2MAX = redmax[0];
#pragma unroll
    for (int i = 1; i < 16; i++) F2MAX = fmaxf(F2MAX, redmax[i]);

    const int iloc = rg * 16 + c;                    // A-fragment row (m = lane&15)
    const float rf1 = f1s[iloc];
    const float zb = rf1 + F2MAX;
    const float rm = fmaxf(zb, 0.2f * zb);           // log2-domain upper bound
    const float Ac = rf1 - rm;                       // s = max(Ac+f2', fma(.2,f2',Bc))
    const float Bc = 0.2f * rf1 - rm;

    f32x4 acc[8];
#pragma unroll
    for (int i = 0; i < 8; i++) acc[i] = (f32x4){0.f, 0.f, 0.f, 0.f};
    float lsum = 0.f;

    for (int kb = 0; kb < 32; kb++) {
        const int jb = jg * 1024 + kb * 32;
        __syncthreads();
#pragma unroll
        for (int e = 0; e < 2; e++) {
            gload_lds16(Wp + (size_t)(rg * 32 + e * 16 + (lane >> 2)) * 4096 + jb + (lane & 3) * 8,
                        (void*)&Bs[jg][(rg * 32 + e * 16) * 32]);
        }
        __syncthreads();
        const unsigned mb = ms[iloc * 528 + jg * 128 + kb * 4 + quad];
        const float4 fa = *(const float4*)&f2s[jb + quad * 8];
        const float4 fb = *(const float4*)&f2s[jb + quad * 8 + 4];
        const float f2v[8] = {fa.x, fa.y, fa.z, fa.w, fb.x, fb.y, fb.z, fb.w};
        union { bf16x8 v; u16 s[8]; } af;
#pragma unroll
        for (int t = 0; t < 8; t++) {
            float s = fmaxf(Ac + f2v[t], __builtin_fmaf(0.2f, f2v[t], Bc));
            float p = __builtin_amdgcn_exp2f(s);
            p = ((mb >> t) & 1u) ? p : 0.f;
            lsum += p;
            af.s[t] = f2bf(p);
        }
#pragma unroll
        for (int nt = 0; nt < 8; nt++) {
            bf16x8 bv = *(const bf16x8*)&Bs[jg][(nt * 16 + c) * 32 + quad * 8];
            acc[nt] = __builtin_amdgcn_mfma_f32_16x16x32_bf16(af.v, bv, acc[nt], 0, 0, 0);
        }
    }

    // per-jgroup row denominator: sum over the 4 quads
    lsum += __shfl_xor(lsum, 16);
    lsum += __shfl_xor(lsum, 32);
    if (quad == 0) lpart[jg][iloc] = lsum;

    // reduce acc across j-groups into red[i][n] (i local, stride 132)
#pragma unroll
    for (int g = 0; g < 4; g++) {
        __syncthreads();
        if (jg == g) {
#pragma unroll
            for (int nt = 0; nt < 8; nt++) {
#pragma unroll
                for (int r = 0; r < 4; r++) {
                    int idx = (rg * 16 + quad * 4 + r) * 132 + nt * 16 + c;
                    if (g == 0) red[idx] = acc[nt][r];
                    else        red[idx] += acc[nt][r];
                }
            }
        }
    }
    __syncthreads();

    // epilogue: thread -> (row = tid>>4, col-octet = tid&15)
    const int row = tid >> 4, cb = tid & 15;
    const float l = lpart[0][row] + lpart[1][row] + lpart[2][row] + lpart[3][row];
    const float linv = 1.0f / l;
    float vv[8];
#pragma unroll
    for (int t = 0; t < 8; t++) {
        float v = red[row * 132 + cb * 8 + t] * linv;
        vv[t] = v > 0.f ? v : __expf(v) - 1.f;       // ELU
    }
    const size_t obase = (size_t)(i0 + row) * ostride + h * 128 + cb * 8;
    if (F32OUT) {
        float* op = (float*)outp + obase;
        *(float4*)op = *(float4*)&vv[0];
        *(float4*)(op + 4) = *(float4*)&vv[4];
    } else {
        uint4 o;
        o.x = (unsigned)f2bf(vv[0]) | ((unsigned)f2bf(vv[1]) << 16);
        o.y = (unsigned)f2bf(vv[2]) | ((unsigned)f2bf(vv[3]) << 16);
        o.z = (unsigned)f2bf(vv[4]) | ((unsigned)f2bf(vv[5]) << 16);
        o.w = (unsigned)f2bf(vv[6]) | ((unsigned)f2bf(vv[7]) << 16);
        *(uint4*)((u16*)outp + obase) = o;
    }
}

// =====================================================================
// head_relation_combined = entity_emb[head] + relation_emb[relation] (fp32)
__global__ __launch_bounds__(256) void k_gather(const int* __restrict__ head,
                                                const int* __restrict__ rel,
                                                const float* __restrict__ ent,
                                                const float* __restrict__ rele,
                                                float* __restrict__ out) {
    int t = blockIdx.x * 256 + threadIdx.x;   // 131072 threads: row*32 + seg
    int row = t >> 5, sg = t & 31;
    int hh = head[row], rr = rel[row];
    float4 a = ((const float4*)(ent + (size_t)hh * 128))[sg];
    float4 b = ((const float4*)(rele + (size_t)rr * 128))[sg];
    float4 o;
    o.x = a.x + b.x; o.y = a.y + b.y; o.z = a.z + b.z; o.w = a.w + b.w;
    ((float4*)(out + (size_t)row * 128))[sg] = o;
}

// =====================================================================
extern "C" void kernel_launch(void* const* d_in, const int* in_sizes, int n_in,
                              void* d_out, int out_size, void* d_ws, size_t ws_size,
                              hipStream_t stream) {
    const int*   head = (const int*)d_in[0];
    const int*   rel  = (const int*)d_in[1];
    const float* adj  = (const float*)d_in[2];
    const float* ent  = (const float*)d_in[3];
    const float* rele = (const float*)d_in[4];
    const float* W0   = (const float*)d_in[5];
    const float* a0   = (const float*)d_in[6];
    const float* Wm   = (const float*)d_in[7];
    const float* am   = (const float*)d_in[8];
    const float* Wo   = (const float*)d_in[9];
    const float* ao   = (const float*)d_in[10];

    char* ws = (char*)d_ws;
    unsigned* mask = (unsigned*)(ws + 0);                 // 2 MB
    u16* WT0 = (u16*)(ws + 2097152);                      // 128 KB
    u16* WT5 = (u16*)(ws + 2228224);                      // 37 * 128 KB = 4.625 MB
    u16* WhT = (u16*)(ws + 7077888);                      // 4 MB
    float* f1 = (float*)(ws + 11272192);                  // 64 KB
    float* f2 = (float*)(ws + 11337728);                  // 64 KB
    u16* xA = (u16*)(ws + 11403264);                      // 4 MB
    u16* xB = (u16*)(ws + 15597568);                      // 4 MB
    u16* x0 = (u16*)(ws + 19791872);                      // 1 MB   (total ~20 MB)

    float* out_x = (float*)d_out;
    float* out_comb = out_x + (size_t)4096 * 128;

    k_mask<<<2048, 256, 0, stream>>>(adj, mask);
    k_cvt<<<512, 256, 0, stream>>>(ent, x0);
    k_trans<<<dim3(4, 4, 4), dim3(32, 8), 0, stream>>>(W0, WT0, 128);
    k_trans<<<dim3(16, 4, 36), dim3(32, 8), 0, stream>>>(Wm, WT5, 512);
    k_trans<<<dim3(16, 4, 1), dim3(32, 8), 0, stream>>>(Wo, WT5 + (size_t)36 * 512 * 128, 512);
    k_gather<<<512, 256, 0, stream>>>(head, rel, ent, rele, out_comb);

    // layer 0 : D -> H*D
    k_proj<<<dim3(64, 4), 256, 0, stream>>>(x0, WT0, a0, WhT, f1, f2, 128);
    k_attn<false><<<dim3(64, 4), 1024, 0, stream>>>(WhT, f1, f2, (const unsigned char*)mask, xA, 512);
    u16 *xc = xA, *xn = xB;
    // 9 middle layers : H*D -> H*D
    for (int l = 0; l < 9; l++) {
        k_proj<<<dim3(64, 4), 256, 0, stream>>>(xc, WT5 + (size_t)l * 4 * 512 * 128,
                                                am + (size_t)l * 4 * 256, WhT, f1, f2, 512);
        k_attn<false><<<dim3(64, 4), 1024, 0, stream>>>(WhT, f1, f2, (const unsigned char*)mask, xn, 512);
        u16* t = xc; xc = xn; xn = t;
    }
    // output layer : H*D -> D, single head, fp32 out
    k_proj<<<dim3(64, 1), 256, 0, stream>>>(xc, WT5 + (size_t)36 * 512 * 128, ao, WhT, f1, f2, 512);
    k_attn<true><<<dim3(64, 1), 1024, 0, stream>>>(WhT, f1, f2, (const unsigned char*)mask, out_x, 128);
}

// Round 4
// 672.146 us; speedup vs baseline: 1.8142x; 1.2589x over previous
//
#include <hip/hip_runtime.h>

typedef unsigned short u16;
typedef short bf16x8 __attribute__((ext_vector_type(8)));
typedef float f32x4 __attribute__((ext_vector_type(4)));

__device__ __forceinline__ float bf2f(unsigned v) { return __uint_as_float(v << 16); }
__device__ __forceinline__ u16 f2bf(float f) {
    unsigned u = __float_as_uint(f);
    return (u16)((u + 0x7fffu + ((u >> 16) & 1u)) >> 16);
}

// ---- async global->LDS, width 16B per lane, dest = wave base + lane*16 ----
__device__ __forceinline__ void gload_lds16(const void* g, void* l) {
    __builtin_amdgcn_global_load_lds(
        (const __attribute__((address_space(1))) unsigned int*)g,
        (__attribute__((address_space(3))) unsigned int*)l, 16, 0, 0);
}

// =====================================================================
// Bitmask: bit j of word w  <=>  adj[w*32 + j] > 0   (adj fp32)
__global__ __launch_bounds__(256) void k_mask(const float* __restrict__ adj,
                                              unsigned* __restrict__ mask) {
    int w = blockIdx.x * 256 + threadIdx.x;           // 524288 words
    const float4* q = (const float4*)(adj + (size_t)w * 32);
    unsigned bits = 0u;
#pragma unroll
    for (int i = 0; i < 8; i++) {
        float4 v = q[i];
        if (v.x > 0.f) bits |= (1u << (i * 4 + 0));
        if (v.y > 0.f) bits |= (1u << (i * 4 + 1));
        if (v.z > 0.f) bits |= (1u << (i * 4 + 2));
        if (v.w > 0.f) bits |= (1u << (i * 4 + 3));
    }
    mask[w] = bits;
}

// =====================================================================
// Transpose [K,128] fp32 -> [128,K] bf16 per matrix (batch = blockIdx.z)
__global__ void k_trans(const float* __restrict__ in, u16* __restrict__ out, int K) {
    __shared__ float t[32][33];
    const float* src = in + (size_t)blockIdx.z * K * 128;
    u16* dst = out + (size_t)blockIdx.z * K * 128;
    int k0 = blockIdx.x * 32, n0 = blockIdx.y * 32;
    int tx = threadIdx.x, ty = threadIdx.y;           // 32 x 8
#pragma unroll
    for (int i = 0; i < 32; i += 8) t[ty + i][tx] = src[(size_t)(k0 + ty + i) * 128 + n0 + tx];
    __syncthreads();
#pragma unroll
    for (int i = 0; i < 32; i += 8) dst[(size_t)(n0 + ty + i) * K + k0 + tx] = f2bf(t[tx][ty + i]);
}

// =====================================================================
// fp32 -> bf16 elementwise (entity embedding), 4 elems/thread
__global__ __launch_bounds__(256) void k_cvt(const float* __restrict__ in,
                                             u16* __restrict__ out) {
    int t = blockIdx.x * 256 + threadIdx.x;
    float4 v = ((const float4*)in)[t];
    uint2 o;
    o.x = (unsigned)f2bf(v.x) | ((unsigned)f2bf(v.y) << 16);
    o.y = (unsigned)f2bf(v.z) | ((unsigned)f2bf(v.w) << 16);
    ((uint2*)out)[t] = o;
}

// =====================================================================
// Projection: Wh = x @ W_h  (M=4096, N=128, K=Fin). X bf16, WT bf16 [n][k],
// avec fp32. Writes WhT[n][j] bf16 and f1/f2 fp32.
// 1024 thr = 16 waves = 4 row-groups x 4 col-groups; double-buffered, one
// barrier per K-iter.
__global__ __launch_bounds__(1024, 4) void k_proj(const u16* __restrict__ X,
                                                  const u16* __restrict__ WT,
                                                  const float* __restrict__ avec,
                                                  u16* __restrict__ WhT,
                                                  float* __restrict__ f1,
                                                  float* __restrict__ f2, int Fin) {
    __shared__ u16 As[2][64 * 32];    // 8 KB  [row][k]
    __shared__ u16 Bs[2][128 * 32];   // 16 KB [n][k]
    __shared__ float fpart[4][64][2]; // per-colgroup f1/f2 partials
    const int tid = threadIdx.x;
    const int wv = tid >> 6, lane = tid & 63;
    const int rg = wv & 3, cg = wv >> 2;
    const int c = lane & 15, quad = lane >> 4;
    const int h = blockIdx.y;
    const int j0 = blockIdx.x * 64;
    const u16* Wp = WT + (size_t)h * 128 * Fin;

    // stage: 12 of 16 waves issue one 1KB gload each (4 As rows-16, 8 Bs rows-16)
#define PROJ_STAGE(buf, kb)                                                              \
    do {                                                                                 \
        if (cg == 0)                                                                     \
            gload_lds16(X + (size_t)(j0 + rg * 16 + (lane >> 2)) * Fin + (kb) + (lane & 3) * 8, \
                        (void*)&As[buf][rg * 16 * 32]);                                  \
        else if (cg <= 2)                                                                \
            gload_lds16(Wp + (size_t)((cg - 1) * 64 + rg * 16 + (lane >> 2)) * Fin + (kb) + (lane & 3) * 8, \
                        (void*)&Bs[buf][((cg - 1) * 64 + rg * 16) * 32]);                \
    } while (0)

    PROJ_STAGE(0, 0);
    __syncthreads();

    f32x4 acc[2];
    acc[0] = (f32x4){0.f, 0.f, 0.f, 0.f};
    acc[1] = (f32x4){0.f, 0.f, 0.f, 0.f};

    int it = 0;
    for (int kb = 0; kb < Fin; kb += 32, it++) {
        const int cur = it & 1;
        if (kb + 32 < Fin) PROJ_STAGE(cur ^ 1, kb + 32);
        bf16x8 av = *(const bf16x8*)&As[cur][(rg * 16 + c) * 32 + quad * 8];
#pragma unroll
        for (int e = 0; e < 2; e++) {
            bf16x8 bv = *(const bf16x8*)&Bs[cur][((cg * 2 + e) * 16 + c) * 32 + quad * 8];
            acc[e] = __builtin_amdgcn_mfma_f32_16x16x32_bf16(av, bv, acc[e], 0, 0, 0);
        }
        __syncthreads();
    }

    // epilogue: C row = rg*16+quad*4+r, col n = (cg*2+e)*16+c
    u16* Wo = WhT + (size_t)h * 128 * 4096;
    const float* ah = avec + h * 256;
    float p1[4] = {0, 0, 0, 0}, p2[4] = {0, 0, 0, 0};
#pragma unroll
    for (int e = 0; e < 2; e++) {
        const int n = (cg * 2 + e) * 16 + c;
        float a1 = ah[n];
        float a2 = ah[128 + n];
        u16 w4[4];
#pragma unroll
        for (int r = 0; r < 4; r++) {
            float v = acc[e][r];
            w4[r] = f2bf(v);
            p1[r] += v * a1;
            p2[r] += v * a2;
        }
        uint2 pk;
        pk.x = (unsigned)w4[0] | ((unsigned)w4[1] << 16);
        pk.y = (unsigned)w4[2] | ((unsigned)w4[3] << 16);
        *(uint2*)&Wo[(size_t)n * 4096 + j0 + rg * 16 + quad * 4] = pk;
    }
#pragma unroll
    for (int off = 1; off < 16; off <<= 1) {
#pragma unroll
        for (int r = 0; r < 4; r++) {
            p1[r] += __shfl_xor(p1[r], off);
            p2[r] += __shfl_xor(p2[r], off);
        }
    }
    if (c == 0) {
#pragma unroll
        for (int r = 0; r < 4; r++) {
            fpart[cg][rg * 16 + quad * 4 + r][0] = p1[r];
            fpart[cg][rg * 16 + quad * 4 + r][1] = p2[r];
        }
    }
    __syncthreads();
    if (tid < 64) {
        float s1 = fpart[0][tid][0] + fpart[1][tid][0] + fpart[2][tid][0] + fpart[3][tid][0];
        float s2 = fpart[0][tid][1] + fpart[1][tid][1] + fpart[2][tid][1] + fpart[3][tid][1];
        f1[h * 4096 + j0 + tid] = s1;
        f2[h * 4096 + j0 + tid] = s2;
    }
}

// =====================================================================
// Fused masked softmax attention + ELU, j-split across 4 wave-groups.
// 1024 thr = 16 waves = 4 row-groups x 4 j-groups (1024 j each).
// Double-buffered Bs, ONE barrier per K-iter (prefetch issued before
// compute so the vmcnt drain at the barrier is already satisfied).
template <bool F32OUT>
__global__ __launch_bounds__(1024, 4) void k_attn(const u16* __restrict__ WhT,
                                                  const float* __restrict__ f1g,
                                                  const float* __restrict__ f2g,
                                                  const unsigned char* __restrict__ maskb,
                                                  void* __restrict__ outp, int ostride) {
    __shared__ float f2s[4096];            // 16 KB (scaled by log2e)
    __shared__ unsigned char ms[64 * 528]; // 33 KB padded mask rows
    __shared__ u16 Bs[2][4][128 * 32];     // 64 KB double-buffered WhT tiles
    __shared__ float f1s[64];
    __shared__ float lpart[4][64];         // per-jgroup row denominators
    __shared__ float redmax[16];
    __shared__ float red[64 * 132];        // 33 KB fp32 acc reduce [i][n], pad 4

    const int tid = threadIdx.x;
    const int wv = tid >> 6, lane = tid & 63;
    const int jg = wv >> 2, rg = wv & 3;
    const int c = lane & 15, quad = lane >> 4;
    const int h = blockIdx.y;
    const int i0 = blockIdx.x * 64;
    const float LOG2E = 1.4426950408889634f;
    const float* f1h = f1g + h * 4096;
    const float* f2h = f2g + h * 4096;
    const u16* Wp = WhT + (size_t)h * 128 * 4096;

#define ATTN_STAGE(buf, kb)                                                              \
    do {                                                                                 \
        const int jb_ = jg * 1024 + (kb) * 32;                                           \
        _Pragma("unroll")                                                                \
        for (int e = 0; e < 2; e++)                                                      \
            gload_lds16(Wp + (size_t)(rg * 32 + e * 16 + (lane >> 2)) * 4096 + jb_ + (lane & 3) * 8, \
                        (void*)&Bs[buf][jg][(rg * 32 + e * 16) * 32]);                   \
    } while (0)

    // stage f2 (scaled), f1 (scaled), mask; issue first Bs tile; block max f2'
    float mymax = -3.0e38f;
    {
        float4 v = ((const float4*)f2h)[tid];
        v.x *= LOG2E; v.y *= LOG2E; v.z *= LOG2E; v.w *= LOG2E;
        ((float4*)f2s)[tid] = v;
        mymax = fmaxf(fmaxf(v.x, v.y), fmaxf(v.z, v.w));
    }
    if (tid < 64) f1s[tid] = f1h[i0 + tid] * LOG2E;
    {   // 64 rows x 512 B of mask = 2048 uint4
        const uint4* msrc = (const uint4*)(maskb + (size_t)i0 * 512);
#pragma unroll
        for (int e = 0; e < 2; e++) {
            int o = tid + e * 1024;
            uint4 v = msrc[o];
            int row = o >> 5, col = o & 31;
            *(uint4*)&ms[row * 528 + col * 16] = v;
        }
    }
    ATTN_STAGE(0, 0);
#pragma unroll
    for (int off = 1; off < 64; off <<= 1) mymax = fmaxf(mymax, __shfl_xor(mymax, off));
    if (lane == 0) redmax[wv] = mymax;
    __syncthreads();
    float F2MAX = redmax[0];
#pragma unroll
    for (int i = 1; i < 16; i++) F2MAX = fmaxf(F2MAX, redmax[i]);

    const int iloc = rg * 16 + c;                    // A-fragment row (m = lane&15)
    const float rf1 = f1s[iloc];
    const float zb = rf1 + F2MAX;
    const float rm = fmaxf(zb, 0.2f * zb);           // log2-domain upper bound
    const float Ac = rf1 - rm;                       // s = max(Ac+f2', fma(.2,f2',Bc))
    const float Bc = 0.2f * rf1 - rm;

    f32x4 acc[8];
#pragma unroll
    for (int i = 0; i < 8; i++) acc[i] = (f32x4){0.f, 0.f, 0.f, 0.f};
    float lsum = 0.f;

    for (int kb = 0; kb < 32; kb++) {
        const int cur = kb & 1;
        if (kb < 31) ATTN_STAGE(cur ^ 1, kb + 1);
        const int jb = jg * 1024 + kb * 32;
        const unsigned mb = ms[iloc * 528 + jg * 128 + kb * 4 + quad];
        const float4 fa = *(const float4*)&f2s[jb + quad * 8];
        const float4 fb = *(const float4*)&f2s[jb + quad * 8 + 4];
        const float f2v[8] = {fa.x, fa.y, fa.z, fa.w, fb.x, fb.y, fb.z, fb.w};
        union { bf16x8 v; unsigned u[4]; } af;
#pragma unroll
        for (int t = 0; t < 8; t += 2) {
            float s0 = fmaxf(Ac + f2v[t],     __builtin_fmaf(0.2f, f2v[t],     Bc));
            float s1 = fmaxf(Ac + f2v[t + 1], __builtin_fmaf(0.2f, f2v[t + 1], Bc));
            float p0 = __builtin_amdgcn_exp2f(s0);
            float p1 = __builtin_amdgcn_exp2f(s1);
            // truncate to bf16 (keeps softmax exactly normalized: lsum uses the
            // same truncated values the MFMA consumes)
            unsigned u0 = ((mb >> t) & 1u)       ? (__float_as_uint(p0) & 0xffff0000u) : 0u;
            unsigned u1 = ((mb >> (t + 1)) & 1u) ? (__float_as_uint(p1) & 0xffff0000u) : 0u;
            lsum += __uint_as_float(u0) + __uint_as_float(u1);
            af.u[t >> 1] = (u0 >> 16) | u1;
        }
#pragma unroll
        for (int nt = 0; nt < 8; nt++) {
            bf16x8 bv = *(const bf16x8*)&Bs[cur][jg][(nt * 16 + c) * 32 + quad * 8];
            acc[nt] = __builtin_amdgcn_mfma_f32_16x16x32_bf16(af.v, bv, acc[nt], 0, 0, 0);
        }
        __syncthreads();
    }

    // per-jgroup row denominator: sum over the 4 quads
    lsum += __shfl_xor(lsum, 16);
    lsum += __shfl_xor(lsum, 32);
    if (quad == 0) lpart[jg][iloc] = lsum;

    // reduce acc across j-groups into red[i][n] (i local, stride 132)
#pragma unroll
    for (int g = 0; g < 4; g++) {
        __syncthreads();
        if (jg == g) {
#pragma unroll
            for (int nt = 0; nt < 8; nt++) {
#pragma unroll
                for (int r = 0; r < 4; r++) {
                    int idx = (rg * 16 + quad * 4 + r) * 132 + nt * 16 + c;
                    if (g == 0) red[idx] = acc[nt][r];
                    else        red[idx] += acc[nt][r];
                }
            }
        }
    }
    __syncthreads();

    // epilogue: thread -> (row = tid>>4, col-octet = tid&15)
    const int row = tid >> 4, cb = tid & 15;
    const float l = lpart[0][row] + lpart[1][row] + lpart[2][row] + lpart[3][row];
    const float linv = 1.0f / l;
    float vv[8];
#pragma unroll
    for (int t = 0; t < 8; t++) {
        float v = red[row * 132 + cb * 8 + t] * linv;
        vv[t] = v > 0.f ? v : __expf(v) - 1.f;       // ELU
    }
    const size_t obase = (size_t)(i0 + row) * ostride + h * 128 + cb * 8;
    if (F32OUT) {
        float* op = (float*)outp + obase;
        *(float4*)op = *(float4*)&vv[0];
        *(float4*)(op + 4) = *(float4*)&vv[4];
    } else {
        uint4 o;
        o.x = (unsigned)f2bf(vv[0]) | ((unsigned)f2bf(vv[1]) << 16);
        o.y = (unsigned)f2bf(vv[2]) | ((unsigned)f2bf(vv[3]) << 16);
        o.z = (unsigned)f2bf(vv[4]) | ((unsigned)f2bf(vv[5]) << 16);
        o.w = (unsigned)f2bf(vv[6]) | ((unsigned)f2bf(vv[7]) << 16);
        *(uint4*)((u16*)outp + obase) = o;
    }
}

// =====================================================================
// head_relation_combined = entity_emb[head] + relation_emb[relation] (fp32)
__global__ __launch_bounds__(256) void k_gather(const int* __restrict__ head,
                                                const int* __restrict__ rel,
                                                const float* __restrict__ ent,
                                                const float* __restrict__ rele,
                                                float* __restrict__ out) {
    int t = blockIdx.x * 256 + threadIdx.x;   // 131072 threads: row*32 + seg
    int row = t >> 5, sg = t & 31;
    int hh = head[row], rr = rel[row];
    float4 a = ((const float4*)(ent + (size_t)hh * 128))[sg];
    float4 b = ((const float4*)(rele + (size_t)rr * 128))[sg];
    float4 o;
    o.x = a.x + b.x; o.y = a.y + b.y; o.z = a.z + b.z; o.w = a.w + b.w;
    ((float4*)(out + (size_t)row * 128))[sg] = o;
}

// =====================================================================
extern "C" void kernel_launch(void* const* d_in, const int* in_sizes, int n_in,
                              void* d_out, int out_size, void* d_ws, size_t ws_size,
                              hipStream_t stream) {
    const int*   head = (const int*)d_in[0];
    const int*   rel  = (const int*)d_in[1];
    const float* adj  = (const float*)d_in[2];
    const float* ent  = (const float*)d_in[3];
    const float* rele = (const float*)d_in[4];
    const float* W0   = (const float*)d_in[5];
    const float* a0   = (const float*)d_in[6];
    const float* Wm   = (const float*)d_in[7];
    const float* am   = (const float*)d_in[8];
    const float* Wo   = (const float*)d_in[9];
    const float* ao   = (const float*)d_in[10];

    char* ws = (char*)d_ws;
    unsigned* mask = (unsigned*)(ws + 0);                 // 2 MB
    u16* WT0 = (u16*)(ws + 2097152);                      // 128 KB
    u16* WT5 = (u16*)(ws + 2228224);                      // 37 * 128 KB = 4.625 MB
    u16* WhT = (u16*)(ws + 7077888);                      // 4 MB
    float* f1 = (float*)(ws + 11272192);                  // 64 KB
    float* f2 = (float*)(ws + 11337728);                  // 64 KB
    u16* xA = (u16*)(ws + 11403264);                      // 4 MB
    u16* xB = (u16*)(ws + 15597568);                      // 4 MB
    u16* x0 = (u16*)(ws + 19791872);                      // 1 MB   (total ~20 MB)

    float* out_x = (float*)d_out;
    float* out_comb = out_x + (size_t)4096 * 128;

    k_mask<<<2048, 256, 0, stream>>>(adj, mask);
    k_cvt<<<512, 256, 0, stream>>>(ent, x0);
    k_trans<<<dim3(4, 4, 4), dim3(32, 8), 0, stream>>>(W0, WT0, 128);
    k_trans<<<dim3(16, 4, 36), dim3(32, 8), 0, stream>>>(Wm, WT5, 512);
    k_trans<<<dim3(16, 4, 1), dim3(32, 8), 0, stream>>>(Wo, WT5 + (size_t)36 * 512 * 128, 512);
    k_gather<<<512, 256, 0, stream>>>(head, rel, ent, rele, out_comb);

    // layer 0 : D -> H*D
    k_proj<<<dim3(64, 4), 1024, 0, stream>>>(x0, WT0, a0, WhT, f1, f2, 128);
    k_attn<false><<<dim3(64, 4), 1024, 0, stream>>>(WhT, f1, f2, (const unsigned char*)mask, xA, 512);
    u16 *xc = xA, *xn = xB;
    // 9 middle layers : H*D -> H*D
    for (int l = 0; l < 9; l++) {
        k_proj<<<dim3(64, 4), 1024, 0, stream>>>(xc, WT5 + (size_t)l * 4 * 512 * 128,
                                                 am + (size_t)l * 4 * 256, WhT, f1, f2, 512);
        k_attn<false><<<dim3(64, 4), 1024, 0, stream>>>(WhT, f1, f2, (const unsigned char*)mask, xn, 512);
        u16* t = xc; xc = xn; xn = t;
    }
    // output layer : H*D -> D, single head, fp32 out
    k_proj<<<dim3(64, 1), 1024, 0, stream>>>(xc, WT5 + (size_t)36 * 512 * 128, ao, WhT, f1, f2, 512);
    k_attn<true><<<dim3(64, 1), 1024, 0, stream>>>(WhT, f1, f2, (const unsigned char*)mask, out_x, 128);
}